// Round 10
// baseline (29.602 us; speedup 1.0000x reference)
//
#include <hip/hip_runtime.h>
#include <math.h>

#define NB 4
#define CC 128
#define HW 784        // 28*28
#define KK 64
#define DD 512
#define TD 8          // d-rows per block
#define BLK 832       // 13 waves; >= HW so each thread owns <=1 pixel
#define UNR 16        // x-load batch width (outstanding loads per wave)

// MEASUREMENT ROUND: identical best-known kernel (R9, 17.57us), launched TWICE
// back-to-back. Stream order serializes the two dispatches; the second
// recomputes and rewrites the identical output (deterministic, no state).
// T2 - T1_baseline isolates the kernel's steady-state duration from the
// fixed graph/launch overhead, which the top-5 rocprof table (crowded by
// fillBuffer rows) cannot show us.
__global__ __launch_bounds__(BLK) void netvlad_fused_kernel(
    const float* __restrict__ x, const float* __restrict__ w,
    const float* __restrict__ b, float* __restrict__ out)
{
    __shared__ float w_s[CC][TD];        // 4 KB, transposed: [c][j]
    __shared__ float feat_s[TD][HW];     // 25 KB
    __shared__ float g_s[TD];

    const int tid = threadIdx.x;
    const int n  = blockIdx.x >> 6;      // 64 d-groups per n
    const int d0 = (blockIdx.x & 63) * TD;
    const bool act = tid < HW;

    // stage the 8x128 weight tile transposed (one-time, 4 KB)
    for (int i = tid; i < CC * TD; i += BLK) {
        int c = i >> 3, j = i & 7;
        w_s[c][j] = w[(size_t)(d0 + j) * CC + c];
    }
    __syncthreads();

    if (act) {
        const float* xp = x + (size_t)n * CC * HW + tid;
        float acc[TD];
        #pragma unroll
        for (int j = 0; j < TD; ++j) acc[j] = 0.f;
        float sq = 0.f;

        // 16-deep software pipeline: issue 16 independent loads, then consume.
        for (int cc = 0; cc < CC; cc += UNR) {
            float xv[UNR];
            #pragma unroll
            for (int u = 0; u < UNR; ++u)
                xv[u] = xp[(size_t)(cc + u) * HW];     // 16 loads in flight
            #pragma unroll
            for (int u = 0; u < UNR; ++u) {
                const int c = cc + u;
                float4 wlo = *(const float4*)&w_s[c][0];   // broadcast b128
                float4 whi = *(const float4*)&w_s[c][4];   // broadcast b128
                float xvu = xv[u];
                sq = fmaf(xvu, xvu, sq);
                acc[0] = fmaf(wlo.x, xvu, acc[0]);
                acc[1] = fmaf(wlo.y, xvu, acc[1]);
                acc[2] = fmaf(wlo.z, xvu, acc[2]);
                acc[3] = fmaf(wlo.w, xvu, acc[3]);
                acc[4] = fmaf(whi.x, xvu, acc[4]);
                acc[5] = fmaf(whi.y, xvu, acc[5]);
                acc[6] = fmaf(whi.z, xvu, acc[6]);
                acc[7] = fmaf(whi.w, xvu, acc[7]);
            }
        }

        float r = 1.0f / fmaxf(sqrtf(sq), 1e-12f);
        #pragma unroll
        for (int j = 0; j < TD; ++j)
            feat_s[j][tid] = fmaf(acc[j], r, b[d0 + j]);
    }
    __syncthreads();

    // Per-row softmax-weighted mean over P=784; wave j (j<8) handles row j.
    const int lane = tid & 63;
    const int wave = tid >> 6;
    if (wave < TD) {
        const int j = wave;
        float m = -INFINITY;
        for (int q = lane; q < HW; q += 64) m = fmaxf(m, feat_s[j][q]);
        #pragma unroll
        for (int off = 32; off; off >>= 1) m = fmaxf(m, __shfl_xor(m, off, 64));
        float s = 0.f, ws = 0.f;
        for (int q = lane; q < HW; q += 64) {
            float f = feat_s[j][q];
            float e = __expf(f - m);
            s += e;
            ws = fmaf(e, f, ws);
        }
        #pragma unroll
        for (int off = 32; off; off >>= 1) {
            s  += __shfl_xor(s, off, 64);
            ws += __shfl_xor(ws, off, 64);
        }
        if (lane == 0) g_s[j] = ws / s;
    }
    __syncthreads();

    // Broadcast across k with a coalesced write: block owns out[n, :, d0:d0+8]
    if (tid < KK * TD) {
        int k = tid >> 3, j = tid & 7;
        out[(size_t)n * KK * DD + (size_t)k * DD + d0 + j] = g_s[j];
    }
}

extern "C" void kernel_launch(void* const* d_in, const int* in_sizes, int n_in,
                              void* d_out, int out_size, void* d_ws, size_t ws_size,
                              hipStream_t stream) {
    const float* x = (const float*)d_in[0];   // (4,128,28,28)
    const float* w = (const float*)d_in[1];   // (512,128)
    const float* b = (const float*)d_in[2];   // (512,)
    // d_in[3] = centroids (64,512): provably unused — softmax over the spatial
    // axis is invariant to the per-(k,d) constant shift, so vlad[n,k,d] is
    // identical for all k.
    float* out = (float*)d_out;               // (4,64,512) fp32

    // Launch twice: second dispatch's marginal time = kernel steady-state dur.
    netvlad_fused_kernel<<<NB * (DD / TD), BLK, 0, stream>>>(x, w, b, out);
    netvlad_fused_kernel<<<NB * (DD / TD), BLK, 0, stream>>>(x, w, b, out);
}

// Round 11
// 17.001 us; speedup vs baseline: 1.7412x; 1.7412x over previous
//
#include <hip/hip_runtime.h>
#include <math.h>

#define NB 4
#define CC 128
#define HW 784        // 28*28
#define KK 64
#define DD 512
#define TD 8          // d-rows per block
#define CH 64         // channels per c-half
#define NPAIR 392     // pixel pairs (784/2)
#define HTH 416       // threads per c-half (392 active + pad to wave mult)
#define BLK 832       // 13 waves

// Thread = (pixel-pair, c-half). Block = (n, 8-d-row group), grid 256.
//   - float2 x loads (2 consecutive pixels, 8B/lane coalesced): VMEM instrs
//     halved vs 1-px/thread at IDENTICAL L2 traffic (x[n] read once/block,
//     each half reads its own 64 channels) and identical 13-wave TLP.
//   - weights staged transposed in LDS, 2 broadcast ds_read_b128 per c,
//     now amortized over 2 pixels (inner LDS reads halved).
//   - c-halves combined once via LDS; feat = (dotL+dotH)*rinv + bias.
//   - waves 0..7: per-row softmax-weighted mean over P=784 (as R4).
//   - vlad[n,k,d] is k-independent (softmax over the spatial axis is invariant
//     to the per-(k,d) centroid shift) -> broadcast write via LDS.
__global__ __launch_bounds__(BLK) void netvlad_fused_kernel(
    const float* __restrict__ x, const float* __restrict__ w,
    const float* __restrict__ b, float* __restrict__ out)
{
    __shared__ float w_s[CC][TD];        // 4 KB, transposed [c][j]
    __shared__ float feat_s[TD][HW];     // 25 KB
    __shared__ float sq_s[HW];           // 3.1 KB
    __shared__ float g_s[TD];

    const int tid = threadIdx.x;
    const int n  = blockIdx.x >> 6;
    const int d0 = (blockIdx.x & 63) * TD;

    // stage the 8x128 weight tile transposed (one-time, 4 KB)
    for (int i = tid; i < CC * TD; i += BLK) {
        int c = i >> 3, j = i & 7;
        w_s[c][j] = w[(size_t)(d0 + j) * CC + c];
    }

    const int  ch  = (tid >= HTH) ? 1 : 0;
    const int  qr  = tid - ch * HTH;      // 0..415
    const bool act = qr < NPAIR;
    const int  q   = act ? qr : (NPAIR - 1);   // clamp, keeps loads in-bounds
    const int  p   = 2 * q;
    const int  cb  = ch * CH;

    __syncthreads();

    const float* xp = x + (size_t)n * CC * HW + (size_t)cb * HW + p;

    float acc0[TD], acc1[TD];
    #pragma unroll
    for (int j = 0; j < TD; ++j) { acc0[j] = 0.f; acc1[j] = 0.f; }
    float sq0 = 0.f, sq1 = 0.f;

    // 8-deep batches: 8 independent float2 loads in flight per chunk
    for (int cc = 0; cc < CH; cc += 8) {
        float2 xv[8];
        #pragma unroll
        for (int u = 0; u < 8; ++u)
            xv[u] = *(const float2*)&xp[(size_t)(cc + u) * HW];
        #pragma unroll
        for (int u = 0; u < 8; ++u) {
            const int c = cb + cc + u;
            float4 wlo = *(const float4*)&w_s[c][0];   // uniform -> broadcast
            float4 whi = *(const float4*)&w_s[c][4];
            float a = xv[u].x, e = xv[u].y;
            sq0 = fmaf(a, a, sq0);
            sq1 = fmaf(e, e, sq1);
            acc0[0] = fmaf(wlo.x, a, acc0[0]);  acc1[0] = fmaf(wlo.x, e, acc1[0]);
            acc0[1] = fmaf(wlo.y, a, acc0[1]);  acc1[1] = fmaf(wlo.y, e, acc1[1]);
            acc0[2] = fmaf(wlo.z, a, acc0[2]);  acc1[2] = fmaf(wlo.z, e, acc1[2]);
            acc0[3] = fmaf(wlo.w, a, acc0[3]);  acc1[3] = fmaf(wlo.w, e, acc1[3]);
            acc0[4] = fmaf(whi.x, a, acc0[4]);  acc1[4] = fmaf(whi.x, e, acc1[4]);
            acc0[5] = fmaf(whi.y, a, acc0[5]);  acc1[5] = fmaf(whi.y, e, acc1[5]);
            acc0[6] = fmaf(whi.z, a, acc0[6]);  acc1[6] = fmaf(whi.z, e, acc1[6]);
            acc0[7] = fmaf(whi.w, a, acc0[7]);  acc1[7] = fmaf(whi.w, e, acc1[7]);
        }
    }

    // combine c-halves through LDS (one-time)
    if (act && ch == 0) {
        sq_s[p] = sq0;  sq_s[p + 1] = sq1;
        #pragma unroll
        for (int j = 0; j < TD; ++j) {
            feat_s[j][p]     = acc0[j];
            feat_s[j][p + 1] = acc1[j];
        }
    }
    __syncthreads();
    if (act && ch == 1) {
        float r0 = 1.0f / fmaxf(sqrtf(sq_s[p] + sq0), 1e-12f);
        float r1 = 1.0f / fmaxf(sqrtf(sq_s[p + 1] + sq1), 1e-12f);
        #pragma unroll
        for (int j = 0; j < TD; ++j) {
            float bj = b[d0 + j];
            feat_s[j][p]     = fmaf(feat_s[j][p]     + acc0[j], r0, bj);
            feat_s[j][p + 1] = fmaf(feat_s[j][p + 1] + acc1[j], r1, bj);
        }
    }
    __syncthreads();

    // Per-row softmax-weighted mean over P=784; wave j (j<8) handles row j.
    const int lane = tid & 63;
    const int wave = tid >> 6;
    if (wave < TD) {
        const int j = wave;
        float m = -INFINITY;
        for (int u = lane; u < HW; u += 64) m = fmaxf(m, feat_s[j][u]);
        #pragma unroll
        for (int off = 32; off; off >>= 1) m = fmaxf(m, __shfl_xor(m, off, 64));
        float s = 0.f, ws = 0.f;
        for (int u = lane; u < HW; u += 64) {
            float f = feat_s[j][u];
            float e = __expf(f - m);
            s += e;
            ws = fmaf(e, f, ws);
        }
        #pragma unroll
        for (int off = 32; off; off >>= 1) {
            s  += __shfl_xor(s, off, 64);
            ws += __shfl_xor(ws, off, 64);
        }
        if (lane == 0) g_s[j] = ws / s;
    }
    __syncthreads();

    // Broadcast across k with a coalesced write: block owns out[n, :, d0:d0+8]
    if (tid < KK * TD) {
        int k = tid >> 3, j = tid & 7;
        out[(size_t)n * KK * DD + (size_t)k * DD + d0 + j] = g_s[j];
    }
}

extern "C" void kernel_launch(void* const* d_in, const int* in_sizes, int n_in,
                              void* d_out, int out_size, void* d_ws, size_t ws_size,
                              hipStream_t stream) {
    const float* x = (const float*)d_in[0];   // (4,128,28,28)
    const float* w = (const float*)d_in[1];   // (512,128)
    const float* b = (const float*)d_in[2];   // (512,)
    // d_in[3] = centroids (64,512): provably unused — softmax over the spatial
    // axis is invariant to the per-(k,d) constant shift, so vlad[n,k,d] is
    // identical for all k.
    float* out = (float*)d_out;               // (4,64,512) fp32

    netvlad_fused_kernel<<<NB * (DD / TD), BLK, 0, stream>>>(x, w, b, out);
}